// Round 10
// baseline (453.743 us; speedup 1.0000x reference)
//
#include <hip/hip_runtime.h>
#include <math.h>

// Problem constants (setup_inputs: S=2048, U=10, D=256)
#define SS   2048
#define UU   10
#define DD   256
#define BB   (SS * UU)   // 20480 rows
#define EPSF 1e-8f

typedef __attribute__((ext_vector_type(8))) short   bf16x8;
typedef __attribute__((ext_vector_type(4))) float   floatx4;

__device__ static inline unsigned short f2bf(float f) {
    union { float f; unsigned u; } v; v.f = f;
    unsigned r = (v.u + 0x7FFFu + ((v.u >> 16) & 1u)) >> 16;  // RNE
    return (unsigned short)r;
}

// GEMM tile config (r5 core shape)
#define BM 128
#define BN 128
#define BK 32
#define NBM2 (BB / BM)       // 160 row-groups; 16 bn-blocks each

// ---- Kernel 1: barrier-free prep (r7, proven) + zero cnt/sumexp/out ----
#define NORM_NBLK (BB / 4)   // 5120
#define CENT_NBLK (SS / 4)   // 512

__global__ __launch_bounds__(256) void prep_kernel(const float* __restrict__ E,
                                                   unsigned short* __restrict__ Enb,
                                                   unsigned short* __restrict__ Cnb,
                                                   float* __restrict__ sumexp,
                                                   int* __restrict__ cnt,
                                                   float* __restrict__ out) {
    const int wid = threadIdx.x >> 6, lane = threadIdx.x & 63;
    const int b = blockIdx.x;

    if (b < NORM_NBLK) {
        if (b < NBM2 && threadIdx.x == 0) cnt[b] = 0;
        const int row = b * 4 + wid;
        const float4 v = ((const float4*)(E + (size_t)row * DD))[lane];
        float ssq = v.x * v.x + v.y * v.y + v.z * v.z + v.w * v.w;
#pragma unroll
        for (int off = 32; off; off >>= 1) ssq += __shfl_xor(ssq, off, 64);
        const float rinv = 1.0f / fmaxf(sqrtf(ssq), EPSF);
        ushort4 o;
        o.x = f2bf(v.x * rinv); o.y = f2bf(v.y * rinv);
        o.z = f2bf(v.z * rinv); o.w = f2bf(v.w * rinv);
        ((ushort4*)(Enb + (size_t)row * DD))[lane] = o;
        if (lane == 0) {
            sumexp[row] = 0.f;
            if (row == 0) out[0] = 0.f;
        }
    } else {
        const int s = (b - NORM_NBLK) * 4 + wid;
        const float* base = E + (size_t)s * UU * DD + lane * 4;
        float4 c = {0.f, 0.f, 0.f, 0.f};
#pragma unroll
        for (int u = 0; u < UU; ++u) {
            const float4 v = *(const float4*)(base + u * DD);
            c.x += v.x; c.y += v.y; c.z += v.z; c.w += v.w;
        }
        c.x *= 0.1f; c.y *= 0.1f; c.z *= 0.1f; c.w *= 0.1f;
        float ssq = c.x * c.x + c.y * c.y + c.z * c.z + c.w * c.w;
#pragma unroll
        for (int off = 32; off; off >>= 1) ssq += __shfl_xor(ssq, off, 64);
        const float rinv = 1.0f / fmaxf(sqrtf(ssq), EPSF);
        ushort4 o;
        o.x = f2bf(c.x * rinv); o.y = f2bf(c.y * rinv);
        o.z = f2bf(c.z * rinv); o.w = f2bf(c.w * rinv);
        ((ushort4*)(Cnb + (size_t)s * DD))[lane] = o;
    }
}

// ---- Kernel 2: VGPR-staged double-buffered GEMM + exp-sum + pos + fused finalize ----
// r5 tile shape (128x128, 2x2 waves, 4x4 of 16x16x32, BK=32, proven swizzle).
// Staging: global -> VGPR (prefetch distance 2) -> ds_write -> raw s_barrier
// with lgkmcnt(0) only, so global loads stay in flight across barriers.
__global__ __launch_bounds__(256) void gemm_lse_kernel(const unsigned short* __restrict__ Enb,
                                                       const unsigned short* __restrict__ Cnb,
                                                       float* __restrict__ posArr,
                                                       float* __restrict__ sumexp,
                                                       int* __restrict__ cnt,
                                                       float* __restrict__ out) {
    __shared__ unsigned short L[2][(BM + BN) * BK];   // 2 x 16 KB (A then B)
    __shared__ int lastflag;

    const int tid  = threadIdx.x;
    const int wid  = tid >> 6, lane = tid & 63;
    const int l15  = lane & 15, quad = lane >> 4;
    const int wave_m = wid >> 1, wave_n = wid & 1;

    const int bn = blockIdx.x & 15;          // SS/BN = 16
    const int bm = blockIdx.x >> 4;          // BB/BM = 160
    const int row0 = bm * BM, n0 = bn * BN;

    // 16 chunks of 1 KB (16 rows x 32k); A: c=0..7, B: c=8..15; 4 per wave.
    // lane -> row rl=lane>>2, slot sl=lane&3 holds logical granule sl^((rl>>1)&3)
    const int rl = lane >> 2;
    const int gf = ((lane & 3) ^ ((rl >> 1) & 3)) * 8;
    const unsigned short* gp[4];
    int lo[4];
#pragma unroll
    for (int i = 0; i < 4; ++i) {
        const int c = wid * 4 + i;
        gp[i] = (c < 8) ? Enb + (size_t)(row0 + c * 16 + rl) * DD + gf
                        : Cnb + (size_t)(n0 + (c - 8) * 16 + rl) * DD + gf;
        lo[i] = c * 512 + lane * 8;          // elem offset in L[buf]
    }

    // fragment offsets (r5, verified conflict-free)
    const int fswz = (quad ^ ((l15 >> 1) & 3)) * 8;
    int aoff[4], boff[4];
#pragma unroll
    for (int t = 0; t < 4; ++t) {
        aoff[t] = (wave_m * 64 + t * 16 + l15) * BK + fswz;
        boff[t] = BM * BK + (wave_n * 64 + t * 16 + l15) * BK + fswz;
    }

    // prologue: stages 0,1 -> VGPRs; write stage 0; light barrier
    uint4 g[2][4];
#pragma unroll
    for (int i = 0; i < 4; ++i) g[0][i] = *(const uint4*)(gp[i]);
#pragma unroll
    for (int i = 0; i < 4; ++i) g[1][i] = *(const uint4*)(gp[i] + 32);
#pragma unroll
    for (int i = 0; i < 4; ++i) *(uint4*)&L[0][lo[i]] = g[0][i];
    asm volatile("s_waitcnt lgkmcnt(0)\n\ts_barrier" ::: "memory");

    floatx4 acc[4][4];
#pragma unroll
    for (int i = 0; i < 4; ++i)
#pragma unroll
        for (int j = 0; j < 4; ++j) acc[i][j] = (floatx4){0.f, 0.f, 0.f, 0.f};

#pragma unroll
    for (int s = 0; s < 8; ++s) {
        // prefetch stage s+2 into the VGPR set just freed by the last ds_write
        if (s < 6) {
#pragma unroll
            for (int i = 0; i < 4; ++i) g[s & 1][i] = *(const uint4*)(gp[i] + (s + 2) * 32);
        }
        const unsigned short* Lc = L[s & 1];
        bf16x8 af[4], bfr[4];
#pragma unroll
        for (int t = 0; t < 4; ++t) af[t]  = *(const bf16x8*)(Lc + aoff[t]);
#pragma unroll
        for (int t = 0; t < 4; ++t) bfr[t] = *(const bf16x8*)(Lc + boff[t]);
#pragma unroll
        for (int mt = 0; mt < 4; ++mt)
#pragma unroll
            for (int nt = 0; nt < 4; ++nt)
                acc[mt][nt] = __builtin_amdgcn_mfma_f32_16x16x32_bf16(af[mt], bfr[nt], acc[mt][nt], 0, 0, 0);
        if (s < 7) {
            // stage s+1 (loaded 2 iters ago) -> other LDS buffer; barrier waits
            // only on LDS (lgkm), global prefetches stay in flight
#pragma unroll
            for (int i = 0; i < 4; ++i) *(uint4*)&L[(s + 1) & 1][lo[i]] = g[(s + 1) & 1][i];
            asm volatile("s_waitcnt lgkmcnt(0)\n\ts_barrier" ::: "memory");
        }
    }

    // epilogue: C/D layout col=l15 (n), row=quad*4+reg (m)
#pragma unroll
    for (int mt = 0; mt < 4; ++mt) {
        float rs[4] = {0.f, 0.f, 0.f, 0.f};
        const int growb = row0 + wave_m * 64 + mt * 16 + quad * 4;
#pragma unroll
        for (int nt = 0; nt < 4; ++nt) {
            const int col = n0 + wave_n * 64 + nt * 16 + l15;
#pragma unroll
            for (int r = 0; r < 4; ++r) {
                const int grow = growb + r;
                const float sim = acc[mt][nt][r];
                if (col == grow / UU) {
                    posArr[grow] = sim;           // excluded from sum (-inf mask)
                } else {
                    rs[r] += __expf(sim);
                }
            }
        }
#pragma unroll
        for (int m = 1; m < 16; m <<= 1) {
#pragma unroll
            for (int r = 0; r < 4; ++r) rs[r] += __shfl_xor(rs[r], m, 64);
        }
        if (l15 == 0) {
#pragma unroll
            for (int r = 0; r < 4; ++r) atomicAdd(&sumexp[growb + r], rs[r]);
        }
    }

    // ---- fused finalize: last of the 16 bn-blocks for this bm does 128 rows
    __threadfence();                              // release this block's writes
    __syncthreads();
    if (tid == 0) lastflag = (atomicAdd(&cnt[bm], 1) == 15);
    __syncthreads();
    if (lastflag) {
        __threadfence();                          // acquire
        float t = 0.f;
        if (tid < BM) {
            const int r = row0 + tid;
            const float se = atomicAdd(&sumexp[r], 0.0f);   // coherent fetch
            const float ps = atomicAdd(&posArr[r], 0.0f);
            t = __logf(se) - ps;
        }
#pragma unroll
        for (int off = 32; off; off >>= 1) t += __shfl_xor(t, off, 64);
        if (lane == 0 && tid < BM) atomicAdd(out, t * (1.0f / (float)BB));
    }
}

extern "C" void kernel_launch(void* const* d_in, const int* in_sizes, int n_in,
                              void* d_out, int out_size, void* d_ws, size_t ws_size,
                              hipStream_t stream) {
    const float* E = (const float*)d_in[0];
    float* out = (float*)d_out;

    unsigned short* Enb = (unsigned short*)d_ws;            // BB*DD bf16 = 10.5 MB
    unsigned short* Cnb = Enb + (size_t)BB * DD;            // SS*DD bf16 = 1 MB
    float* posArr = (float*)(Cnb + (size_t)SS * DD);        // BB floats
    float* sumexp = posArr + BB;                            // BB floats (zeroed by prep)
    int*   cnt    = (int*)(sumexp + BB);                    // NBM2 ints (zeroed by prep)

    prep_kernel<<<NORM_NBLK + CENT_NBLK, 256, 0, stream>>>(E, Enb, Cnb, sumexp, cnt, out);
    gemm_lse_kernel<<<NBM2 * 16, 256, 0, stream>>>(Enb, Cnb, posArr, sumexp, cnt, out);
}